// Round 1
// baseline (144.498 us; speedup 1.0000x reference)
//
#include <hip/hip_runtime.h>
#include <math.h>

#define N_INC   12288
#define N_EDGES 6144
#define N_TRI   4096

// ---- ordered-uint encoding for float atomicMax (handles negatives) ----
__device__ __forceinline__ unsigned enc_f(float f) {
    int b = __float_as_int(f);
    return (b >= 0) ? (unsigned(b) | 0x80000000u) : ~unsigned(b);
}
__device__ __forceinline__ float dec_f(unsigned u) {
    int b = (u & 0x80000000u) ? int(u & 0x7FFFFFFFu) : int(~u);
    return __int_as_float(b);
}

__device__ __forceinline__ float gelu_exact(float x) {
    return 0.5f * x * (1.0f + erff(x * 0.70710678118654752f));
}

// K1: q,k,v projections + triangle member counts
__global__ void k_qkv(const float* __restrict__ ef, const int* __restrict__ tri,
                      const float* __restrict__ Wq, const float* __restrict__ bq,
                      const float* __restrict__ Wk, const float* __restrict__ bk,
                      const float* __restrict__ Wv, const float* __restrict__ bv,
                      float* __restrict__ q, float* __restrict__ k, float* __restrict__ v,
                      int* __restrict__ counts) {
    int i = blockIdx.x * blockDim.x + threadIdx.x;
    if (i >= N_INC) return;
    float x0 = ef[i * 2], x1 = ef[i * 2 + 1];
#pragma unroll
    for (int d = 0; d < 8; d++) {
        q[i * 8 + d] = Wq[d * 2] * x0 + Wq[d * 2 + 1] * x1 + bq[d];
        k[i * 8 + d] = Wk[d * 2] * x0 + Wk[d * 2 + 1] * x1 + bk[d];
        v[i * 8 + d] = Wv[d * 2] * x0 + Wv[d * 2 + 1] * x1 + bv[d];
    }
    atomicAdd(&counts[tri[i]], 1);
}

// K2: exclusive scan over 4096 counts (single block, 1024 threads, 4 elems/thread)
__global__ void k_scan(const int* __restrict__ counts,
                       int* __restrict__ offsets, int* __restrict__ cursor) {
    __shared__ int lds[1024];
    int t = threadIdx.x;
    int c0 = counts[t * 4 + 0], c1 = counts[t * 4 + 1];
    int c2 = counts[t * 4 + 2], c3 = counts[t * 4 + 3];
    int s = c0 + c1 + c2 + c3;
    lds[t] = s;
    __syncthreads();
    for (int off = 1; off < 1024; off <<= 1) {
        int val = (t >= off) ? lds[t - off] : 0;
        __syncthreads();
        lds[t] += val;
        __syncthreads();
    }
    int base = lds[t] - s;  // exclusive prefix
    int o0 = base, o1 = base + c0, o2 = o1 + c1, o3 = o2 + c2;
    offsets[t * 4 + 0] = o0; offsets[t * 4 + 1] = o1;
    offsets[t * 4 + 2] = o2; offsets[t * 4 + 3] = o3;
    cursor[t * 4 + 0] = o0;  cursor[t * 4 + 1] = o1;
    cursor[t * 4 + 2] = o2;  cursor[t * 4 + 3] = o3;
    if (t == 1023) offsets[4096] = lds[1023];
}

// K3: fill member lists
__global__ void k_fill(const int* __restrict__ tri, int* __restrict__ cursor,
                       int* __restrict__ list) {
    int i = blockIdx.x * blockDim.x + threadIdx.x;
    if (i >= N_INC) return;
    int pos = atomicAdd(&cursor[tri[i]], 1);
    list[pos] = i;
}

// K4: per-row sparse attention (online softmax over triangle group) + full MLP + logit
__global__ void __launch_bounds__(64)
k_main(const float* __restrict__ q, const float* __restrict__ k, const float* __restrict__ v,
       const int* __restrict__ tri, const int* __restrict__ eid,
       const int* __restrict__ offsets, const int* __restrict__ list,
       const float* __restrict__ W1, const float* __restrict__ b1,
       const float* __restrict__ ln1g, const float* __restrict__ ln1b,
       const float* __restrict__ rmsw,
       const float* __restrict__ Wr, const float* __restrict__ br,
       const float* __restrict__ ln2g, const float* __restrict__ ln2b,
       const float* __restrict__ W2, const float* __restrict__ b2,
       const float* __restrict__ W3, const float* __restrict__ b3,
       float* __restrict__ logits, unsigned* __restrict__ segmax) {
    int i = blockIdx.x * blockDim.x + threadIdx.x;
    if (i >= N_INC) return;

    float qi[8];
#pragma unroll
    for (int d = 0; d < 8; d++) qi[d] = q[i * 8 + d];

    int t = tri[i];
    int s0 = offsets[t], s1 = offsets[t + 1];

    float m = -1e30f, l = 0.f, acc[8];
#pragma unroll
    for (int d = 0; d < 8; d++) acc[d] = 0.f;

    for (int p = s0; p < s1; p++) {
        int j = list[p];
        float sc = 0.f;
#pragma unroll
        for (int d = 0; d < 8; d++) sc += qi[d] * k[j * 8 + d];
        sc *= 0.35355339059327373f;  // 1/sqrt(8)
        float nm = fmaxf(m, sc);
        float scale = expf(m - nm);
        float w = expf(sc - nm);
        l = l * scale + w;
#pragma unroll
        for (int d = 0; d < 8; d++) acc[d] = acc[d] * scale + w * v[j * 8 + d];
        m = nm;
    }
    float inv_l = 1.f / l;
    float att[8];
#pragma unroll
    for (int d = 0; d < 8; d++) att[d] = acc[d] * inv_l;

    // ---- MLP (all in registers; weights are wave-uniform -> s_loads) ----
    float h[32];
#pragma unroll
    for (int o = 0; o < 32; o++) {
        float a = b1[o];
#pragma unroll
        for (int d = 0; d < 8; d++) a += W1[o * 8 + d] * att[d];
        h[o] = a;
    }
    // LayerNorm 1
    {
        float mu = 0.f;
#pragma unroll
        for (int o = 0; o < 32; o++) mu += h[o];
        mu *= (1.f / 32.f);
        float var = 0.f;
#pragma unroll
        for (int o = 0; o < 32; o++) { float d = h[o] - mu; var += d * d; }
        var *= (1.f / 32.f);
        float is = 1.f / sqrtf(var + 1e-5f);
#pragma unroll
        for (int o = 0; o < 32; o++) h[o] = (h[o] - mu) * is * ln1g[o] + ln1b[o];
    }
    // GELU (exact)
#pragma unroll
    for (int o = 0; o < 32; o++) h[o] = gelu_exact(h[o]);
    // ResBlock: h += relu(Wr @ rmsnorm(h) + br)
    {
        float ss = 0.f;
#pragma unroll
        for (int o = 0; o < 32; o++) ss += h[o] * h[o];
        float rms = sqrtf(ss * (1.f / 32.f));
        float ir = 1.f / (rms + 1e-6f);
        float hn[32];
#pragma unroll
        for (int o = 0; o < 32; o++) hn[o] = h[o] * ir * rmsw[o];
#pragma unroll
        for (int o = 0; o < 32; o++) {
            float a = br[o];
#pragma unroll
            for (int in = 0; in < 32; in++) a += Wr[o * 32 + in] * hn[in];
            h[o] += fmaxf(a, 0.f);
        }
    }
    // LayerNorm 2
    {
        float mu = 0.f;
#pragma unroll
        for (int o = 0; o < 32; o++) mu += h[o];
        mu *= (1.f / 32.f);
        float var = 0.f;
#pragma unroll
        for (int o = 0; o < 32; o++) { float d = h[o] - mu; var += d * d; }
        var *= (1.f / 32.f);
        float is = 1.f / sqrtf(var + 1e-5f);
#pragma unroll
        for (int o = 0; o < 32; o++) h[o] = (h[o] - mu) * is * ln2g[o] + ln2b[o];
    }
    // Linear 32->16 + GELU
    float h2[16];
#pragma unroll
    for (int o = 0; o < 16; o++) {
        float a = b2[o];
#pragma unroll
        for (int in = 0; in < 32; in++) a += W2[o * 32 + in] * h[in];
        h2[o] = gelu_exact(a);
    }
    // Linear 16->1
    float lg = b3[0];
#pragma unroll
    for (int in = 0; in < 16; in++) lg += W3[in] * h2[in];

    logits[i] = lg;
    atomicMax(&segmax[eid[i]], enc_f(lg));
}

// K5: e = exp(logit - segmax); segment sum
__global__ void k_exp(const float* __restrict__ logits, const int* __restrict__ eid,
                      const unsigned* __restrict__ segmax, float* __restrict__ ebuf,
                      float* __restrict__ segsum) {
    int i = blockIdx.x * blockDim.x + threadIdx.x;
    if (i >= N_INC) return;
    float sm = dec_f(segmax[eid[i]]);
    float ex = expf(logits[i] - sm);
    ebuf[i] = ex;
    atomicAdd(&segsum[eid[i]], ex);
}

// K6: normalize
__global__ void k_final(const float* __restrict__ ebuf, const int* __restrict__ eid,
                        const float* __restrict__ segsum, float* __restrict__ out) {
    int i = blockIdx.x * blockDim.x + threadIdx.x;
    if (i >= N_INC) return;
    out[i] = ebuf[i] / segsum[eid[i]];
}

extern "C" void kernel_launch(void* const* d_in, const int* in_sizes, int n_in,
                              void* d_out, int out_size, void* d_ws, size_t ws_size,
                              hipStream_t stream) {
    const float* ef   = (const float*)d_in[0];
    const int*   eid  = (const int*)d_in[1];
    const int*   tri  = (const int*)d_in[2];
    const float* Wq   = (const float*)d_in[3];  const float* bq = (const float*)d_in[4];
    const float* Wk   = (const float*)d_in[5];  const float* bk = (const float*)d_in[6];
    const float* Wv   = (const float*)d_in[7];  const float* bv = (const float*)d_in[8];
    const float* W1   = (const float*)d_in[9];  const float* b1 = (const float*)d_in[10];
    const float* ln1g = (const float*)d_in[11]; const float* ln1b = (const float*)d_in[12];
    const float* rmsw = (const float*)d_in[13];
    const float* Wr   = (const float*)d_in[14]; const float* br = (const float*)d_in[15];
    const float* ln2g = (const float*)d_in[16]; const float* ln2b = (const float*)d_in[17];
    const float* W2   = (const float*)d_in[18]; const float* b2 = (const float*)d_in[19];
    const float* W3   = (const float*)d_in[20]; const float* b3 = (const float*)d_in[21];

    // workspace layout (floats/ints, all 4-byte)
    float* ws     = (float*)d_ws;
    float* q      = ws;
    float* kk     = q + N_INC * 8;
    float* vv     = kk + N_INC * 8;
    float* logits = vv + N_INC * 8;
    float* ebuf   = logits + N_INC;
    float* segsum = ebuf + N_INC;                       // N_EDGES
    unsigned* segmax = (unsigned*)(segsum + N_EDGES);   // N_EDGES
    int* counts   = (int*)(segmax + N_EDGES);           // N_TRI
    int* offsets  = counts + N_TRI;                     // N_TRI + 1
    int* cursor   = offsets + N_TRI + 1;                // N_TRI
    int* list     = cursor + N_TRI;                     // N_INC

    // zero segsum | segmax | counts (contiguous)
    hipMemsetAsync(segsum, 0, (size_t)(2 * N_EDGES + N_TRI) * sizeof(int), stream);

    const int B = 256;
    const int G = (N_INC + B - 1) / B;

    k_qkv<<<G, B, 0, stream>>>(ef, tri, Wq, bq, Wk, bk, Wv, bv, q, kk, vv, counts);
    k_scan<<<1, 1024, 0, stream>>>(counts, offsets, cursor);
    k_fill<<<G, B, 0, stream>>>(tri, cursor, list);
    k_main<<<(N_INC + 63) / 64, 64, 0, stream>>>(q, kk, vv, tri, eid, offsets, list,
                                                 W1, b1, ln1g, ln1b, rmsw, Wr, br,
                                                 ln2g, ln2b, W2, b2, W3, b3,
                                                 logits, segmax);
    k_exp<<<G, B, 0, stream>>>(logits, eid, segmax, ebuf, segsum);
    k_final<<<G, B, 0, stream>>>(ebuf, eid, segsum, (float*)d_out);
}